// Round 5
// baseline (291.496 us; speedup 1.0000x reference)
//
#include <hip/hip_runtime.h>

#define DEV __device__ __forceinline__

typedef __bf16 bf16x8 __attribute__((ext_vector_type(8)));
typedef float f32x4 __attribute__((ext_vector_type(4)));
typedef short short8v __attribute__((ext_vector_type(8)));

static constexpr int Tn = 2048;
static constexpr int Dn = 1024;
static constexpr int NHn = 32;
static constexpr int Mn = 2 * Tn;  // B*T = 4096
static constexpr float QSCALE = 0.17677669529663687f * 1.4426950408889634f;  // 1/sqrt(32)*log2e

DEV unsigned short f2bf(float f) {
    unsigned int u = __builtin_bit_cast(unsigned int, f);
    u = u + 0x7FFFu + ((u >> 16) & 1u);
    return (unsigned short)(u >> 16);
}

#define GPTR(p) ((const __attribute__((address_space(1))) void*)(p))
#define LPTR(p) ((__attribute__((address_space(3))) void*)(p))

// ---------------- single fused cast: x (1M float4) + 4 weights (1M float4) ----------------
__global__ __launch_bounds__(256) void cast_all(
    const float* __restrict__ x, const float* __restrict__ Wq, const float* __restrict__ Wk,
    const float* __restrict__ Wv, const float* __restrict__ Wp,
    unsigned short* __restrict__ xb, unsigned short* __restrict__ wall) {
    int i = blockIdx.x * 256 + threadIdx.x;  // [0, 2M)
    const float* src;
    ushort4* dst;
    if (i < (1 << 20)) {
        src = x + (size_t)i * 4;
        dst = reinterpret_cast<ushort4*>(xb) + i;
    } else {
        int j = i - (1 << 20);
        int sel = j >> 18, off = j & ((1 << 18) - 1);
        const float* w = (sel == 0) ? Wq : (sel == 1) ? Wk : (sel == 2) ? Wv : Wp;
        src = w + (size_t)off * 4;
        dst = reinterpret_cast<ushort4*>(wall) + ((size_t)sel << 18) + off;
    }
    float4 v = *reinterpret_cast<const float4*>(src);
    ushort4 o;
    o.x = f2bf(v.x); o.y = f2bf(v.y); o.z = f2bf(v.z); o.w = f2bf(v.w);
    *dst = o;
}

// ---------------- fused QKV GEMM (m97 pattern) + RMSNorm/RoPE/relayout epilogue ----------------
__global__ __launch_bounds__(256, 3) void gemm_qkv(
    const unsigned short* __restrict__ A, const unsigned short* __restrict__ Wall,
    unsigned short* __restrict__ Qn, unsigned short* __restrict__ Kn, unsigned short* __restrict__ Vt,
    const float* __restrict__ gain, const float* __restrict__ cosp, const float* __restrict__ sinp) {
    const int z = blockIdx.z;
    const unsigned short* Bm = Wall + (size_t)z * (Dn * Dn);
    const int m0 = blockIdx.x * 128, n0 = blockIdx.y * 128;
    const int tid = threadIdx.x, w = tid >> 6, l = tid & 63;
    const int wm = w & 1, wn = w >> 1, lm = l & 15, quad = l >> 4;

    __shared__ __align__(16) unsigned short As[128 * 32];  // lane-linear, no padding (global_load_lds)
    __shared__ __align__(16) unsigned short Bs[128 * 32];

    f32x4 acc[4][4] = {};

    const int r0 = (w * 2 + 0) * 16 + (l >> 2);
    const int r1 = (w * 2 + 1) * 16 + (l >> 2);
    const int c0 = (l & 3) * 8;
    const unsigned short* gA0 = A + (long)(m0 + r0) * Dn + c0;
    const unsigned short* gA1 = A + (long)(m0 + r1) * Dn + c0;
    const unsigned short* gB0 = Bm + (long)(n0 + r0) * Dn + c0;
    const unsigned short* gB1 = Bm + (long)(n0 + r1) * Dn + c0;
    unsigned short* lA0 = As + (w * 2 + 0) * 16 * 32;
    unsigned short* lA1 = As + (w * 2 + 1) * 16 * 32;
    unsigned short* lB0 = Bs + (w * 2 + 0) * 16 * 32;
    unsigned short* lB1 = Bs + (w * 2 + 1) * 16 * 32;

    for (int kk = 0; kk < Dn; kk += 32) {
        __builtin_amdgcn_global_load_lds(GPTR(gA0 + kk), LPTR(lA0), 16, 0, 0);
        __builtin_amdgcn_global_load_lds(GPTR(gA1 + kk), LPTR(lA1), 16, 0, 0);
        __builtin_amdgcn_global_load_lds(GPTR(gB0 + kk), LPTR(lB0), 16, 0, 0);
        __builtin_amdgcn_global_load_lds(GPTR(gB1 + kk), LPTR(lB1), 16, 0, 0);
        __syncthreads();
        bf16x8 af[4], bfv[4];
#pragma unroll
        for (int mt = 0; mt < 4; ++mt)
            af[mt] = __builtin_bit_cast(bf16x8,
                *reinterpret_cast<const uint4*>(As + (wm * 64 + mt * 16 + lm) * 32 + quad * 8));
#pragma unroll
        for (int nt = 0; nt < 4; ++nt)
            bfv[nt] = __builtin_bit_cast(bf16x8,
                *reinterpret_cast<const uint4*>(Bs + (wn * 64 + nt * 16 + lm) * 32 + quad * 8));
#pragma unroll
        for (int mt = 0; mt < 4; ++mt)
#pragma unroll
            for (int nt = 0; nt < 4; ++nt)
                acc[mt][nt] = __builtin_amdgcn_mfma_f32_16x16x32_bf16(af[mt], bfv[nt], acc[mt][nt], 0, 0, 0);
        __syncthreads();
    }

    if (z == 2) {
#pragma unroll
        for (int mt = 0; mt < 4; ++mt) {
            int row0 = m0 + wm * 64 + mt * 16 + quad * 4;
            int b_ = row0 >> 11, t_ = row0 & (Tn - 1);
#pragma unroll
            for (int nt = 0; nt < 4; ++nt) {
                int col = n0 + wn * 64 + nt * 16 + lm;
                int hh = col >> 5, dd = col & 31;
                ushort4 o4;
                o4.x = f2bf(acc[mt][nt][0]); o4.y = f2bf(acc[mt][nt][1]);
                o4.z = f2bf(acc[mt][nt][2]); o4.w = f2bf(acc[mt][nt][3]);
                *reinterpret_cast<ushort4*>(&Vt[((long)(b_ * NHn + hh) * 32 + dd) * Tn + t_]) = o4;
            }
        }
    } else {
        unsigned short* dst = z ? Kn : Qn;
#pragma unroll
        for (int mt = 0; mt < 4; ++mt)
#pragma unroll
            for (int r = 0; r < 4; ++r) {
                int row = m0 + wm * 64 + mt * 16 + quad * 4 + r;
                int b_ = row >> 11, t_ = row & (Tn - 1);
                float c = cosp[t_ * 16 + lm], s = sinp[t_ * 16 + lm];
#pragma unroll
                for (int g = 0; g < 2; ++g) {
                    float x1 = acc[mt][2 * g][r], x2 = acc[mt][2 * g + 1][r];
                    float ssv = x1 * x1 + x2 * x2;
#pragma unroll
                    for (int off = 8; off >= 1; off >>= 1) ssv += __shfl_xor(ssv, off, 16);
                    float rinv = rsqrtf(ssv * (1.0f / 32.0f) + 1e-6f);
                    x1 *= rinv; x2 *= rinv;
                    float o1 = x1 * c - x2 * s;
                    float o2 = x2 * c + x1 * s;
                    int hh = (n0 + wn * 64 + g * 32) >> 5;
                    if (z == 0) { float gs = gain[hh] * QSCALE; o1 *= gs; o2 *= gs; }
                    long base = ((long)(b_ * NHn + hh) * Tn + t_) * 32;
                    dst[base + lm] = f2bf(o1);
                    dst[base + 16 + lm] = f2bf(o2);
                }
            }
    }
}

// ---------------- proj GEMM: 128x64 tile (512 blocks -> 2 blocks/CU), fp32 out ----------------
__global__ __launch_bounds__(256, 3) void gemm_proj(
    const unsigned short* __restrict__ A, const unsigned short* __restrict__ Bm,
    float* __restrict__ C) {
    const int m0 = blockIdx.x * 128, n0 = blockIdx.y * 64;
    const int tid = threadIdx.x, w = tid >> 6, l = tid & 63;
    const int wm = w & 1, wn = w >> 1, lm = l & 15, quad = l >> 4;

    __shared__ __align__(16) unsigned short As[128 * 32];
    __shared__ __align__(16) unsigned short Bs[64 * 32];

    f32x4 acc[4][2] = {};

    const int r0 = (w * 2 + 0) * 16 + (l >> 2);
    const int r1 = (w * 2 + 1) * 16 + (l >> 2);
    const int rb = w * 16 + (l >> 2);
    const int c0 = (l & 3) * 8;
    const unsigned short* gA0 = A + (long)(m0 + r0) * Dn + c0;
    const unsigned short* gA1 = A + (long)(m0 + r1) * Dn + c0;
    const unsigned short* gB0 = Bm + (long)(n0 + rb) * Dn + c0;
    unsigned short* lA0 = As + (w * 2 + 0) * 16 * 32;
    unsigned short* lA1 = As + (w * 2 + 1) * 16 * 32;
    unsigned short* lB0 = Bs + w * 16 * 32;

    for (int kk = 0; kk < Dn; kk += 32) {
        __builtin_amdgcn_global_load_lds(GPTR(gA0 + kk), LPTR(lA0), 16, 0, 0);
        __builtin_amdgcn_global_load_lds(GPTR(gA1 + kk), LPTR(lA1), 16, 0, 0);
        __builtin_amdgcn_global_load_lds(GPTR(gB0 + kk), LPTR(lB0), 16, 0, 0);
        __syncthreads();
        bf16x8 af[4], bfv[2];
#pragma unroll
        for (int mt = 0; mt < 4; ++mt)
            af[mt] = __builtin_bit_cast(bf16x8,
                *reinterpret_cast<const uint4*>(As + (wm * 64 + mt * 16 + lm) * 32 + quad * 8));
#pragma unroll
        for (int nt = 0; nt < 2; ++nt)
            bfv[nt] = __builtin_bit_cast(bf16x8,
                *reinterpret_cast<const uint4*>(Bs + (wn * 32 + nt * 16 + lm) * 32 + quad * 8));
#pragma unroll
        for (int mt = 0; mt < 4; ++mt)
#pragma unroll
            for (int nt = 0; nt < 2; ++nt)
                acc[mt][nt] = __builtin_amdgcn_mfma_f32_16x16x32_bf16(af[mt], bfv[nt], acc[mt][nt], 0, 0, 0);
        __syncthreads();
    }
#pragma unroll
    for (int mt = 0; mt < 4; ++mt)
#pragma unroll
        for (int nt = 0; nt < 2; ++nt)
#pragma unroll
            for (int r = 0; r < 4; ++r) {
                int rg = m0 + wm * 64 + mt * 16 + quad * 4 + r;
                int cg = n0 + wn * 32 + nt * 16 + lm;
                C[(long)rg * Dn + cg] = acc[mt][nt][r];
            }
}

// ---------------- flash attention: S^T trick, P in registers, permuted-K PV, zero LDS ----------------
// S^T = K·Q^T: C-layout gives lane -> q=lane&15, k=quad*4+r. PV uses 16x16x32 MFMA with a
// permuted k-axis: hardware slot (quad, j=il*4+r) holds actual k = k0+kh*32+il*16+quad*4+r in
// BOTH the P (A) and V (B) operands, so the reduction is exact (MFMA sums all 32 slots).
// V B-frags are two 8B loads at that exact t-run — no shuffles, no LDS.
__global__ __launch_bounds__(256) void attn(
    const unsigned short* __restrict__ Qn, const unsigned short* __restrict__ Kn,
    const unsigned short* __restrict__ Vt, unsigned short* __restrict__ Y) {
    const int qb = 15 - blockIdx.x, h = blockIdx.y, b = blockIdx.z;
    const int tid = threadIdx.x, w = tid >> 6, l = tid & 63;
    const int lm = l & 15, quad = l >> 4;
    const int q0 = qb * 128 + w * 32;
    const long bh = b * NHn + h;
    const unsigned short* Qh = Qn + bh * Tn * 32;
    const unsigned short* Kh = Kn + bh * Tn * 32;
    const unsigned short* Vh = Vt + bh * 32 * Tn;

    bf16x8 qf[2];
    float negM[2], lpart[2] = {0.f, 0.f};
    f32x4 o[2][2] = {{{0.f, 0.f, 0.f, 0.f}, {0.f, 0.f, 0.f, 0.f}},
                     {{0.f, 0.f, 0.f, 0.f}, {0.f, 0.f, 0.f, 0.f}}};
#pragma unroll
    for (int t = 0; t < 2; ++t) {
        qf[t] = __builtin_bit_cast(bf16x8,
            *reinterpret_cast<const uint4*>(Qh + (q0 + t * 16 + lm) * 32 + quad * 8));
        float ss = 0.f;
#pragma unroll
        for (int j = 0; j < 8; ++j) { float v = (float)qf[t][j]; ss += v * v; }
        ss += __shfl_xor(ss, 16);
        ss += __shfl_xor(ss, 32);
        negM[t] = -__builtin_sqrtf(ss * 32.0f);  // exact bound: |q_row| * sqrt(32) >= any score
    }

    const int kend = q0 + 31;
    uint4 ka[4], kb[4];

    auto load_k = [&](uint4* kd, int k0) {
#pragma unroll
        for (int i = 0; i < 4; ++i)
            kd[i] = *reinterpret_cast<const uint4*>(Kh + (k0 + i * 16 + lm) * 32 + quad * 8);
    };

    auto compute_t = [&](const uint4* kd, int k0) {
        // V fragments: lane (lm, quad), block i -> V[d=nh*16+lm][t = k0+i*16+quad*4 .. +3]
        uint2 vd[8];
#pragma unroll
        for (int i = 0; i < 4; ++i)
#pragma unroll
            for (int nh_ = 0; nh_ < 2; ++nh_)
                vd[i * 2 + nh_] = *reinterpret_cast<const uint2*>(
                    Vh + (nh_ * 16 + lm) * Tn + k0 + i * 16 + quad * 4);
#pragma unroll
        for (int t = 0; t < 2; ++t) {
            if (k0 > q0 + t * 16 + 15) continue;
            const int qrow = q0 + t * 16 + lm;  // this lane's q-row
            f32x4 s[4];
#pragma unroll
            for (int i = 0; i < 4; ++i) {
                f32x4 zz = {0.f, 0.f, 0.f, 0.f};
                // S^T = K·Q^T: A=K rows (m=k_idx), B=Q rows (n=q)
                s[i] = __builtin_amdgcn_mfma_f32_16x16x32_bf16(
                    __builtin_bit_cast(bf16x8, kd[i]), qf[t], zz, 0, 0, 0);
            }
            const bool full = (k0 + 63) <= (q0 + t * 16);
            const float nm = negM[t];
            float ls = lpart[t];
            short8v pk[2];  // pk[kh][il*4+r] = P at k = k0+kh*32+il*16+quad*4+r
#pragma unroll
            for (int i = 0; i < 4; ++i)
#pragma unroll
                for (int r = 0; r < 4; ++r) {
                    float p = __builtin_amdgcn_exp2f(s[i][r] + nm);
                    if (!full) {
                        int kc = k0 + i * 16 + quad * 4 + r;
                        p = (kc <= qrow) ? p : 0.0f;
                    }
                    ls += p;
                    pk[i >> 1][(i & 1) * 4 + r] = (short)f2bf(p);
                }
            lpart[t] = ls;
#pragma unroll
            for (int kh = 0; kh < 2; ++kh) {
                bf16x8 pa = __builtin_bit_cast(bf16x8, pk[kh]);
#pragma unroll
                for (int nh_ = 0; nh_ < 2; ++nh_) {
                    uint2 b0 = vd[(2 * kh) * 2 + nh_], b1 = vd[(2 * kh + 1) * 2 + nh_];
                    uint4 bb = {b0.x, b0.y, b1.x, b1.y};
                    o[t][nh_] = __builtin_amdgcn_mfma_f32_16x16x32_bf16(
                        pa, __builtin_bit_cast(bf16x8, bb), o[t][nh_], 0, 0, 0);
                }
            }
        }
    };

    load_k(ka, 0);
    int k0 = 0;
    while (true) {
        int nk = k0 + 64;
        if (nk <= kend) load_k(kb, nk);
        compute_t(ka, k0);
        if (nk > kend) break;
        k0 = nk;
        nk = k0 + 64;
        if (nk <= kend) load_k(ka, nk);
        compute_t(kb, k0);
        if (nk > kend) break;
        k0 = nk;
    }

#pragma unroll
    for (int t = 0; t < 2; ++t) {
        float lsum = lpart[t];
        lsum += __shfl_xor(lsum, 16);
        lsum += __shfl_xor(lsum, 32);
#pragma unroll
        for (int r = 0; r < 4; ++r) {
            float inv = 1.0f / __shfl(lsum, quad * 4 + r, 16);
            int qrow = q0 + t * 16 + quad * 4 + r;
            long base = ((long)(b * Tn + qrow) * NHn + h) * 32;
            Y[base + lm] = f2bf(o[t][0][r] * inv);
            Y[base + 16 + lm] = f2bf(o[t][1][r] * inv);
        }
    }
}

extern "C" void kernel_launch(void* const* d_in, const int* in_sizes, int n_in,
                              void* d_out, int out_size, void* d_ws, size_t ws_size,
                              hipStream_t stream) {
    (void)in_sizes; (void)n_in; (void)out_size; (void)ws_size;
    const float* x = (const float*)d_in[0];
    const float* Wq = (const float*)d_in[1];
    const float* Wk = (const float*)d_in[2];
    const float* Wv = (const float*)d_in[3];
    const float* Wp = (const float*)d_in[4];
    const float* gain = (const float*)d_in[5];
    const float* cosp = (const float*)d_in[6];
    const float* sinp = (const float*)d_in[7];

    char* ws = (char*)d_ws;
    const size_t SZ = (size_t)Mn * Dn * 2;  // 8 MB
    unsigned short* xb = (unsigned short*)ws;
    unsigned short* wall = (unsigned short*)(ws + SZ);  // [Wq|Wk|Wv|Wp], 8 MB
    unsigned short* qn = (unsigned short*)(ws + 2 * SZ);
    unsigned short* kn = qn + (size_t)Mn * Dn;
    unsigned short* vt = kn + (size_t)Mn * Dn;
    unsigned short* ybuf = vt + (size_t)Mn * Dn;
    // total ws: 48 MB

    cast_all<<<8192, 256, 0, stream>>>(x, Wq, Wk, Wv, Wp, xb, wall);

    gemm_qkv<<<dim3(Mn / 128, Dn / 128, 3), 256, 0, stream>>>(
        xb, wall, qn, kn, vt, gain, cosp, sinp);

    attn<<<dim3(16, NHn, 2), 256, 0, stream>>>(qn, kn, vt, ybuf);

    gemm_proj<<<dim3(Mn / 128, Dn / 64), 256, 0, stream>>>(
        ybuf, wall + (size_t)3 * Dn * Dn, (float*)d_out);
}

// Round 6
// 289.214 us; speedup vs baseline: 1.0079x; 1.0079x over previous
//
#include <hip/hip_runtime.h>

#define DEV __device__ __forceinline__

typedef __bf16 bf16x8 __attribute__((ext_vector_type(8)));
typedef float f32x4 __attribute__((ext_vector_type(4)));
typedef short short8v __attribute__((ext_vector_type(8)));

static constexpr int Tn = 2048;
static constexpr int Dn = 1024;
static constexpr int NHn = 32;
static constexpr int Mn = 2 * Tn;  // B*T = 4096
static constexpr float QSCALE = 0.17677669529663687f * 1.4426950408889634f;  // 1/sqrt(32)*log2e

DEV unsigned short f2bf(float f) {  // RNE
    unsigned int u = __builtin_bit_cast(unsigned int, f);
    u = u + 0x7FFFu + ((u >> 16) & 1u);
    return (unsigned short)(u >> 16);
}
DEV unsigned short f2bf_fast(float f) {  // round-half-up: 2 ops, fine for P in [0,1]
    unsigned int u = __builtin_bit_cast(unsigned int, f);
    return (unsigned short)((u + 0x8000u) >> 16);
}

#define GPTR(p) ((const __attribute__((address_space(1))) void*)(p))
#define LPTR(p) ((__attribute__((address_space(3))) void*)(p))

// ---------------- single fused cast: x (1M float4) + 4 weights (1M float4) ----------------
__global__ __launch_bounds__(256) void cast_all(
    const float* __restrict__ x, const float* __restrict__ Wq, const float* __restrict__ Wk,
    const float* __restrict__ Wv, const float* __restrict__ Wp,
    unsigned short* __restrict__ xb, unsigned short* __restrict__ wall) {
    int i = blockIdx.x * 256 + threadIdx.x;  // [0, 2M)
    const float* src;
    ushort4* dst;
    if (i < (1 << 20)) {
        src = x + (size_t)i * 4;
        dst = reinterpret_cast<ushort4*>(xb) + i;
    } else {
        int j = i - (1 << 20);
        int sel = j >> 18, off = j & ((1 << 18) - 1);
        const float* w = (sel == 0) ? Wq : (sel == 1) ? Wk : (sel == 2) ? Wv : Wp;
        src = w + (size_t)off * 4;
        dst = reinterpret_cast<ushort4*>(wall) + ((size_t)sel << 18) + off;
    }
    float4 v = *reinterpret_cast<const float4*>(src);
    ushort4 o;
    o.x = f2bf(v.x); o.y = f2bf(v.y); o.z = f2bf(v.z); o.w = f2bf(v.w);
    *dst = o;
}

// ---------------- fused QKV GEMM (m97 pattern) + RMSNorm/RoPE/relayout epilogue ----------------
__global__ __launch_bounds__(256, 3) void gemm_qkv(
    const unsigned short* __restrict__ A, const unsigned short* __restrict__ Wall,
    unsigned short* __restrict__ Qn, unsigned short* __restrict__ Kn, unsigned short* __restrict__ Vt,
    const float* __restrict__ gain, const float* __restrict__ cosp, const float* __restrict__ sinp) {
    const int z = blockIdx.z;
    const unsigned short* Bm = Wall + (size_t)z * (Dn * Dn);
    const int m0 = blockIdx.x * 128, n0 = blockIdx.y * 128;
    const int tid = threadIdx.x, w = tid >> 6, l = tid & 63;
    const int wm = w & 1, wn = w >> 1, lm = l & 15, quad = l >> 4;

    __shared__ __align__(16) unsigned short As[128 * 32];  // lane-linear, no padding (global_load_lds)
    __shared__ __align__(16) unsigned short Bs[128 * 32];

    f32x4 acc[4][4] = {};

    const int r0 = (w * 2 + 0) * 16 + (l >> 2);
    const int r1 = (w * 2 + 1) * 16 + (l >> 2);
    const int c0 = (l & 3) * 8;
    const unsigned short* gA0 = A + (long)(m0 + r0) * Dn + c0;
    const unsigned short* gA1 = A + (long)(m0 + r1) * Dn + c0;
    const unsigned short* gB0 = Bm + (long)(n0 + r0) * Dn + c0;
    const unsigned short* gB1 = Bm + (long)(n0 + r1) * Dn + c0;
    unsigned short* lA0 = As + (w * 2 + 0) * 16 * 32;
    unsigned short* lA1 = As + (w * 2 + 1) * 16 * 32;
    unsigned short* lB0 = Bs + (w * 2 + 0) * 16 * 32;
    unsigned short* lB1 = Bs + (w * 2 + 1) * 16 * 32;

    for (int kk = 0; kk < Dn; kk += 32) {
        __builtin_amdgcn_global_load_lds(GPTR(gA0 + kk), LPTR(lA0), 16, 0, 0);
        __builtin_amdgcn_global_load_lds(GPTR(gA1 + kk), LPTR(lA1), 16, 0, 0);
        __builtin_amdgcn_global_load_lds(GPTR(gB0 + kk), LPTR(lB0), 16, 0, 0);
        __builtin_amdgcn_global_load_lds(GPTR(gB1 + kk), LPTR(lB1), 16, 0, 0);
        __syncthreads();
        bf16x8 af[4], bfv[4];
#pragma unroll
        for (int mt = 0; mt < 4; ++mt)
            af[mt] = __builtin_bit_cast(bf16x8,
                *reinterpret_cast<const uint4*>(As + (wm * 64 + mt * 16 + lm) * 32 + quad * 8));
#pragma unroll
        for (int nt = 0; nt < 4; ++nt)
            bfv[nt] = __builtin_bit_cast(bf16x8,
                *reinterpret_cast<const uint4*>(Bs + (wn * 64 + nt * 16 + lm) * 32 + quad * 8));
#pragma unroll
        for (int mt = 0; mt < 4; ++mt)
#pragma unroll
            for (int nt = 0; nt < 4; ++nt)
                acc[mt][nt] = __builtin_amdgcn_mfma_f32_16x16x32_bf16(af[mt], bfv[nt], acc[mt][nt], 0, 0, 0);
        __syncthreads();
    }

    if (z == 2) {
#pragma unroll
        for (int mt = 0; mt < 4; ++mt) {
            int row0 = m0 + wm * 64 + mt * 16 + quad * 4;
            int b_ = row0 >> 11, t_ = row0 & (Tn - 1);
#pragma unroll
            for (int nt = 0; nt < 4; ++nt) {
                int col = n0 + wn * 64 + nt * 16 + lm;
                int hh = col >> 5, dd = col & 31;
                ushort4 o4;
                o4.x = f2bf(acc[mt][nt][0]); o4.y = f2bf(acc[mt][nt][1]);
                o4.z = f2bf(acc[mt][nt][2]); o4.w = f2bf(acc[mt][nt][3]);
                *reinterpret_cast<ushort4*>(&Vt[((long)(b_ * NHn + hh) * 32 + dd) * Tn + t_]) = o4;
            }
        }
    } else {
        unsigned short* dst = z ? Kn : Qn;
#pragma unroll
        for (int mt = 0; mt < 4; ++mt)
#pragma unroll
            for (int r = 0; r < 4; ++r) {
                int row = m0 + wm * 64 + mt * 16 + quad * 4 + r;
                int b_ = row >> 11, t_ = row & (Tn - 1);
                float c = cosp[t_ * 16 + lm], s = sinp[t_ * 16 + lm];
#pragma unroll
                for (int g = 0; g < 2; ++g) {
                    float x1 = acc[mt][2 * g][r], x2 = acc[mt][2 * g + 1][r];
                    float ssv = x1 * x1 + x2 * x2;
#pragma unroll
                    for (int off = 8; off >= 1; off >>= 1) ssv += __shfl_xor(ssv, off, 16);
                    float rinv = rsqrtf(ssv * (1.0f / 32.0f) + 1e-6f);
                    x1 *= rinv; x2 *= rinv;
                    float o1 = x1 * c - x2 * s;
                    float o2 = x2 * c + x1 * s;
                    int hh = (n0 + wn * 64 + g * 32) >> 5;
                    if (z == 0) { float gs = gain[hh] * QSCALE; o1 *= gs; o2 *= gs; }
                    long base = ((long)(b_ * NHn + hh) * Tn + t_) * 32;
                    dst[base + lm] = f2bf(o1);
                    dst[base + 16 + lm] = f2bf(o2);
                }
            }
    }
}

// ---------------- proj GEMM: 128x64 tile (512 blocks -> 2 blocks/CU), fp32 out ----------------
__global__ __launch_bounds__(256, 3) void gemm_proj(
    const unsigned short* __restrict__ A, const unsigned short* __restrict__ Bm,
    float* __restrict__ C) {
    const int m0 = blockIdx.x * 128, n0 = blockIdx.y * 64;
    const int tid = threadIdx.x, w = tid >> 6, l = tid & 63;
    const int wm = w & 1, wn = w >> 1, lm = l & 15, quad = l >> 4;

    __shared__ __align__(16) unsigned short As[128 * 32];
    __shared__ __align__(16) unsigned short Bs[64 * 32];

    f32x4 acc[4][2] = {};

    const int r0 = (w * 2 + 0) * 16 + (l >> 2);
    const int r1 = (w * 2 + 1) * 16 + (l >> 2);
    const int rb = w * 16 + (l >> 2);
    const int c0 = (l & 3) * 8;
    const unsigned short* gA0 = A + (long)(m0 + r0) * Dn + c0;
    const unsigned short* gA1 = A + (long)(m0 + r1) * Dn + c0;
    const unsigned short* gB0 = Bm + (long)(n0 + rb) * Dn + c0;
    unsigned short* lA0 = As + (w * 2 + 0) * 16 * 32;
    unsigned short* lA1 = As + (w * 2 + 1) * 16 * 32;
    unsigned short* lB0 = Bs + w * 16 * 32;

    for (int kk = 0; kk < Dn; kk += 32) {
        __builtin_amdgcn_global_load_lds(GPTR(gA0 + kk), LPTR(lA0), 16, 0, 0);
        __builtin_amdgcn_global_load_lds(GPTR(gA1 + kk), LPTR(lA1), 16, 0, 0);
        __builtin_amdgcn_global_load_lds(GPTR(gB0 + kk), LPTR(lB0), 16, 0, 0);
        __syncthreads();
        bf16x8 af[4], bfv[2];
#pragma unroll
        for (int mt = 0; mt < 4; ++mt)
            af[mt] = __builtin_bit_cast(bf16x8,
                *reinterpret_cast<const uint4*>(As + (wm * 64 + mt * 16 + lm) * 32 + quad * 8));
#pragma unroll
        for (int nt = 0; nt < 2; ++nt)
            bfv[nt] = __builtin_bit_cast(bf16x8,
                *reinterpret_cast<const uint4*>(Bs + (wn * 32 + nt * 16 + lm) * 32 + quad * 8));
#pragma unroll
        for (int mt = 0; mt < 4; ++mt)
#pragma unroll
            for (int nt = 0; nt < 2; ++nt)
                acc[mt][nt] = __builtin_amdgcn_mfma_f32_16x16x32_bf16(af[mt], bfv[nt], acc[mt][nt], 0, 0, 0);
        __syncthreads();
    }
#pragma unroll
    for (int mt = 0; mt < 4; ++mt)
#pragma unroll
        for (int nt = 0; nt < 2; ++nt)
#pragma unroll
            for (int r = 0; r < 4; ++r) {
                int rg = m0 + wm * 64 + mt * 16 + quad * 4 + r;
                int cg = n0 + wn * 32 + nt * 16 + lm;
                C[(long)rg * Dn + cg] = acc[mt][nt][r];
            }
}

// ---------------- flash attention: S^T + permuted-K PV (verified r5) + K&V ping-pong prefetch ----
// S^T = K·Q^T: lane -> q=lane&15, k=quad*4+r (A-layout-compatible). PV via 16x16x32 with permuted
// k-slots; V fragments are 8B loads matching slot pattern. K AND V prefetched one tile ahead in
// registers (round-3's proven latency fix). Grid 16x32x2, big tiles first.
__global__ __launch_bounds__(256) void attn(
    const unsigned short* __restrict__ Qn, const unsigned short* __restrict__ Kn,
    const unsigned short* __restrict__ Vt, unsigned short* __restrict__ Y) {
    const int qb = 15 - blockIdx.x, h = blockIdx.y, b = blockIdx.z;
    const int tid = threadIdx.x, w = tid >> 6, l = tid & 63;
    const int lm = l & 15, quad = l >> 4;
    const int q0 = qb * 128 + w * 32;
    const long bh = b * NHn + h;
    const unsigned short* Qh = Qn + bh * Tn * 32;
    const unsigned short* Kh = Kn + bh * Tn * 32;
    const unsigned short* Vh = Vt + bh * 32 * Tn;

    bf16x8 qf[2];
    float negM[2], lpart[2] = {0.f, 0.f};
    f32x4 o[2][2] = {{{0.f, 0.f, 0.f, 0.f}, {0.f, 0.f, 0.f, 0.f}},
                     {{0.f, 0.f, 0.f, 0.f}, {0.f, 0.f, 0.f, 0.f}}};
#pragma unroll
    for (int t = 0; t < 2; ++t) {
        qf[t] = __builtin_bit_cast(bf16x8,
            *reinterpret_cast<const uint4*>(Qh + (q0 + t * 16 + lm) * 32 + quad * 8));
        float ss = 0.f;
#pragma unroll
        for (int j = 0; j < 8; ++j) { float v = (float)qf[t][j]; ss += v * v; }
        ss += __shfl_xor(ss, 16);
        ss += __shfl_xor(ss, 32);
        negM[t] = -__builtin_sqrtf(ss * 32.0f);  // exact bound: |q_row| * sqrt(32) >= any score
    }

    const int kend = q0 + 31;
    uint4 ka[4], kb[4];
    uint2 va[8], vb[8];

    auto load_t = [&](uint4* kd, uint2* vd, int k0) {
#pragma unroll
        for (int i = 0; i < 4; ++i)
            kd[i] = *reinterpret_cast<const uint4*>(Kh + (k0 + i * 16 + lm) * 32 + quad * 8);
#pragma unroll
        for (int i = 0; i < 4; ++i)
#pragma unroll
            for (int nh_ = 0; nh_ < 2; ++nh_)
                vd[i * 2 + nh_] = *reinterpret_cast<const uint2*>(
                    Vh + (nh_ * 16 + lm) * Tn + k0 + i * 16 + quad * 4);
    };

    auto compute_t = [&](const uint4* kd, const uint2* vd, int k0) {
#pragma unroll
        for (int t = 0; t < 2; ++t) {
            if (k0 > q0 + t * 16 + 15) continue;
            const int qrow = q0 + t * 16 + lm;  // this lane's q-row
            f32x4 s[4];
#pragma unroll
            for (int i = 0; i < 4; ++i) {
                f32x4 zz = {0.f, 0.f, 0.f, 0.f};
                // S^T = K·Q^T: A=K rows (m=k_idx), B=Q rows (n=q)
                s[i] = __builtin_amdgcn_mfma_f32_16x16x32_bf16(
                    __builtin_bit_cast(bf16x8, kd[i]), qf[t], zz, 0, 0, 0);
            }
            const bool full = (k0 + 63) <= (q0 + t * 16);
            const float nm = negM[t];
            float ls = lpart[t];
            short8v pk[2];  // pk[kh][il*4+r] = P at k = k0+kh*32+il*16+quad*4+r
#pragma unroll
            for (int i = 0; i < 4; ++i)
#pragma unroll
                for (int r = 0; r < 4; ++r) {
                    float p = __builtin_amdgcn_exp2f(s[i][r] + nm);
                    if (!full) {
                        int kc = k0 + i * 16 + quad * 4 + r;
                        p = (kc <= qrow) ? p : 0.0f;
                    }
                    ls += p;
                    pk[i >> 1][(i & 1) * 4 + r] = (short)f2bf_fast(p);
                }
            lpart[t] = ls;
#pragma unroll
            for (int kh = 0; kh < 2; ++kh) {
                bf16x8 pa = __builtin_bit_cast(bf16x8, pk[kh]);
#pragma unroll
                for (int nh_ = 0; nh_ < 2; ++nh_) {
                    uint2 b0 = vd[(2 * kh) * 2 + nh_], b1 = vd[(2 * kh + 1) * 2 + nh_];
                    uint4 bb = {b0.x, b0.y, b1.x, b1.y};
                    o[t][nh_] = __builtin_amdgcn_mfma_f32_16x16x32_bf16(
                        pa, __builtin_bit_cast(bf16x8, bb), o[t][nh_], 0, 0, 0);
                }
            }
        }
    };

    load_t(ka, va, 0);
    int k0 = 0;
    while (true) {
        int nk = k0 + 64;
        if (nk <= kend) load_t(kb, vb, nk);
        compute_t(ka, va, k0);
        if (nk > kend) break;
        k0 = nk;
        nk = k0 + 64;
        if (nk <= kend) load_t(ka, va, nk);
        compute_t(kb, vb, k0);
        if (nk > kend) break;
        k0 = nk;
    }

#pragma unroll
    for (int t = 0; t < 2; ++t) {
        float lsum = lpart[t];
        lsum += __shfl_xor(lsum, 16);
        lsum += __shfl_xor(lsum, 32);
#pragma unroll
        for (int r = 0; r < 4; ++r) {
            float inv = 1.0f / __shfl(lsum, quad * 4 + r, 16);
            int qrow = q0 + t * 16 + quad * 4 + r;
            long base = ((long)(b * Tn + qrow) * NHn + h) * 32;
            Y[base + lm] = f2bf(o[t][0][r] * inv);
            Y[base + 16 + lm] = f2bf(o[t][1][r] * inv);
        }
    }
}

extern "C" void kernel_launch(void* const* d_in, const int* in_sizes, int n_in,
                              void* d_out, int out_size, void* d_ws, size_t ws_size,
                              hipStream_t stream) {
    (void)in_sizes; (void)n_in; (void)out_size; (void)ws_size;
    const float* x = (const float*)d_in[0];
    const float* Wq = (const float*)d_in[1];
    const float* Wk = (const float*)d_in[2];
    const float* Wv = (const float*)d_in[3];
    const float* Wp = (const float*)d_in[4];
    const float* gain = (const float*)d_in[5];
    const float* cosp = (const float*)d_in[6];
    const float* sinp = (const float*)d_in[7];

    char* ws = (char*)d_ws;
    const size_t SZ = (size_t)Mn * Dn * 2;  // 8 MB
    unsigned short* xb = (unsigned short*)ws;
    unsigned short* wall = (unsigned short*)(ws + SZ);  // [Wq|Wk|Wv|Wp], 8 MB
    unsigned short* qn = (unsigned short*)(ws + 2 * SZ);
    unsigned short* kn = qn + (size_t)Mn * Dn;
    unsigned short* vt = kn + (size_t)Mn * Dn;
    unsigned short* ybuf = vt + (size_t)Mn * Dn;
    // total ws: 48 MB

    cast_all<<<8192, 256, 0, stream>>>(x, Wq, Wk, Wv, Wp, xb, wall);

    gemm_qkv<<<dim3(Mn / 128, Dn / 128, 3), 256, 0, stream>>>(
        xb, wall, qn, kn, vt, gain, cosp, sinp);

    attn<<<dim3(16, NHn, 2), 256, 0, stream>>>(qn, kn, vt, ybuf);

    gemm_proj<<<dim3(Mn / 128, Dn / 64), 256, 0, stream>>>(
        ybuf, wall + (size_t)3 * Dn * Dn, (float*)d_out);
}

// Round 7
// 287.963 us; speedup vs baseline: 1.0123x; 1.0043x over previous
//
#include <hip/hip_runtime.h>

#define DEV __device__ __forceinline__

typedef __bf16 bf16x8 __attribute__((ext_vector_type(8)));
typedef float f32x4 __attribute__((ext_vector_type(4)));
typedef short short8v __attribute__((ext_vector_type(8)));

static constexpr int Tn = 2048;
static constexpr int Dn = 1024;
static constexpr int NHn = 32;
static constexpr int Mn = 2 * Tn;  // B*T = 4096
static constexpr float QSCALE = 0.17677669529663687f * 1.4426950408889634f;  // 1/sqrt(32)*log2e

DEV unsigned short f2bf(float f) {  // RNE
    unsigned int u = __builtin_bit_cast(unsigned int, f);
    u = u + 0x7FFFu + ((u >> 16) & 1u);
    return (unsigned short)(u >> 16);
}
DEV unsigned short f2bf_fast(float f) {  // round-half-up: 2 ops, fine for P in [0,1]
    unsigned int u = __builtin_bit_cast(unsigned int, f);
    return (unsigned short)((u + 0x8000u) >> 16);
}

#define GPTR(p) ((const __attribute__((address_space(1))) void*)(p))
#define LPTR(p) ((__attribute__((address_space(3))) void*)(p))

// ---------------- single fused cast: x (1M float4) + 4 weights (1M float4) ----------------
__global__ __launch_bounds__(256) void cast_all(
    const float* __restrict__ x, const float* __restrict__ Wq, const float* __restrict__ Wk,
    const float* __restrict__ Wv, const float* __restrict__ Wp,
    unsigned short* __restrict__ xb, unsigned short* __restrict__ wall) {
    int i = blockIdx.x * 256 + threadIdx.x;  // [0, 2M)
    const float* src;
    ushort4* dst;
    if (i < (1 << 20)) {
        src = x + (size_t)i * 4;
        dst = reinterpret_cast<ushort4*>(xb) + i;
    } else {
        int j = i - (1 << 20);
        int sel = j >> 18, off = j & ((1 << 18) - 1);
        const float* w = (sel == 0) ? Wq : (sel == 1) ? Wk : (sel == 2) ? Wv : Wp;
        src = w + (size_t)off * 4;
        dst = reinterpret_cast<ushort4*>(wall) + ((size_t)sel << 18) + off;
    }
    float4 v = *reinterpret_cast<const float4*>(src);
    ushort4 o;
    o.x = f2bf(v.x); o.y = f2bf(v.y); o.z = f2bf(v.z); o.w = f2bf(v.w);
    *dst = o;
}

// ---------------- fused QKV GEMM (m97 pattern) + RMSNorm/RoPE/relayout epilogue ----------------
__global__ __launch_bounds__(256, 3) void gemm_qkv(
    const unsigned short* __restrict__ A, const unsigned short* __restrict__ Wall,
    unsigned short* __restrict__ Qn, unsigned short* __restrict__ Kn, unsigned short* __restrict__ Vt,
    const float* __restrict__ gain, const float* __restrict__ cosp, const float* __restrict__ sinp) {
    const int z = blockIdx.z;
    const unsigned short* Bm = Wall + (size_t)z * (Dn * Dn);
    const int m0 = blockIdx.x * 128, n0 = blockIdx.y * 128;
    const int tid = threadIdx.x, w = tid >> 6, l = tid & 63;
    const int wm = w & 1, wn = w >> 1, lm = l & 15, quad = l >> 4;

    __shared__ __align__(16) unsigned short As[128 * 32];  // lane-linear, no padding (global_load_lds)
    __shared__ __align__(16) unsigned short Bs[128 * 32];

    f32x4 acc[4][4] = {};

    const int r0 = (w * 2 + 0) * 16 + (l >> 2);
    const int r1 = (w * 2 + 1) * 16 + (l >> 2);
    const int c0 = (l & 3) * 8;
    const unsigned short* gA0 = A + (long)(m0 + r0) * Dn + c0;
    const unsigned short* gA1 = A + (long)(m0 + r1) * Dn + c0;
    const unsigned short* gB0 = Bm + (long)(n0 + r0) * Dn + c0;
    const unsigned short* gB1 = Bm + (long)(n0 + r1) * Dn + c0;
    unsigned short* lA0 = As + (w * 2 + 0) * 16 * 32;
    unsigned short* lA1 = As + (w * 2 + 1) * 16 * 32;
    unsigned short* lB0 = Bs + (w * 2 + 0) * 16 * 32;
    unsigned short* lB1 = Bs + (w * 2 + 1) * 16 * 32;

    for (int kk = 0; kk < Dn; kk += 32) {
        __builtin_amdgcn_global_load_lds(GPTR(gA0 + kk), LPTR(lA0), 16, 0, 0);
        __builtin_amdgcn_global_load_lds(GPTR(gA1 + kk), LPTR(lA1), 16, 0, 0);
        __builtin_amdgcn_global_load_lds(GPTR(gB0 + kk), LPTR(lB0), 16, 0, 0);
        __builtin_amdgcn_global_load_lds(GPTR(gB1 + kk), LPTR(lB1), 16, 0, 0);
        __syncthreads();
        bf16x8 af[4], bfv[4];
#pragma unroll
        for (int mt = 0; mt < 4; ++mt)
            af[mt] = __builtin_bit_cast(bf16x8,
                *reinterpret_cast<const uint4*>(As + (wm * 64 + mt * 16 + lm) * 32 + quad * 8));
#pragma unroll
        for (int nt = 0; nt < 4; ++nt)
            bfv[nt] = __builtin_bit_cast(bf16x8,
                *reinterpret_cast<const uint4*>(Bs + (wn * 64 + nt * 16 + lm) * 32 + quad * 8));
#pragma unroll
        for (int mt = 0; mt < 4; ++mt)
#pragma unroll
            for (int nt = 0; nt < 4; ++nt)
                acc[mt][nt] = __builtin_amdgcn_mfma_f32_16x16x32_bf16(af[mt], bfv[nt], acc[mt][nt], 0, 0, 0);
        __syncthreads();
    }

    if (z == 2) {
#pragma unroll
        for (int mt = 0; mt < 4; ++mt) {
            int row0 = m0 + wm * 64 + mt * 16 + quad * 4;
            int b_ = row0 >> 11, t_ = row0 & (Tn - 1);
#pragma unroll
            for (int nt = 0; nt < 4; ++nt) {
                int col = n0 + wn * 64 + nt * 16 + lm;
                int hh = col >> 5, dd = col & 31;
                ushort4 o4;
                o4.x = f2bf(acc[mt][nt][0]); o4.y = f2bf(acc[mt][nt][1]);
                o4.z = f2bf(acc[mt][nt][2]); o4.w = f2bf(acc[mt][nt][3]);
                *reinterpret_cast<ushort4*>(&Vt[((long)(b_ * NHn + hh) * 32 + dd) * Tn + t_]) = o4;
            }
        }
    } else {
        unsigned short* dst = z ? Kn : Qn;
#pragma unroll
        for (int mt = 0; mt < 4; ++mt)
#pragma unroll
            for (int r = 0; r < 4; ++r) {
                int row = m0 + wm * 64 + mt * 16 + quad * 4 + r;
                int b_ = row >> 11, t_ = row & (Tn - 1);
                float c = cosp[t_ * 16 + lm], s = sinp[t_ * 16 + lm];
#pragma unroll
                for (int g = 0; g < 2; ++g) {
                    float x1 = acc[mt][2 * g][r], x2 = acc[mt][2 * g + 1][r];
                    float ssv = x1 * x1 + x2 * x2;
#pragma unroll
                    for (int off = 8; off >= 1; off >>= 1) ssv += __shfl_xor(ssv, off, 16);
                    float rinv = rsqrtf(ssv * (1.0f / 32.0f) + 1e-6f);
                    x1 *= rinv; x2 *= rinv;
                    float o1 = x1 * c - x2 * s;
                    float o2 = x2 * c + x1 * s;
                    int hh = (n0 + wn * 64 + g * 32) >> 5;
                    if (z == 0) { float gs = gain[hh] * QSCALE; o1 *= gs; o2 *= gs; }
                    long base = ((long)(b_ * NHn + hh) * Tn + t_) * 32;
                    dst[base + lm] = f2bf(o1);
                    dst[base + 16 + lm] = f2bf(o2);
                }
            }
    }
}

// ---------------- proj GEMM: 128x64 tile (512 blocks -> 2 blocks/CU), fp32 out ----------------
__global__ __launch_bounds__(256, 3) void gemm_proj(
    const unsigned short* __restrict__ A, const unsigned short* __restrict__ Bm,
    float* __restrict__ C) {
    const int m0 = blockIdx.x * 128, n0 = blockIdx.y * 64;
    const int tid = threadIdx.x, w = tid >> 6, l = tid & 63;
    const int wm = w & 1, wn = w >> 1, lm = l & 15, quad = l >> 4;

    __shared__ __align__(16) unsigned short As[128 * 32];
    __shared__ __align__(16) unsigned short Bs[64 * 32];

    f32x4 acc[4][2] = {};

    const int r0 = (w * 2 + 0) * 16 + (l >> 2);
    const int r1 = (w * 2 + 1) * 16 + (l >> 2);
    const int rb = w * 16 + (l >> 2);
    const int c0 = (l & 3) * 8;
    const unsigned short* gA0 = A + (long)(m0 + r0) * Dn + c0;
    const unsigned short* gA1 = A + (long)(m0 + r1) * Dn + c0;
    const unsigned short* gB0 = Bm + (long)(n0 + rb) * Dn + c0;
    unsigned short* lA0 = As + (w * 2 + 0) * 16 * 32;
    unsigned short* lA1 = As + (w * 2 + 1) * 16 * 32;
    unsigned short* lB0 = Bs + w * 16 * 32;

    for (int kk = 0; kk < Dn; kk += 32) {
        __builtin_amdgcn_global_load_lds(GPTR(gA0 + kk), LPTR(lA0), 16, 0, 0);
        __builtin_amdgcn_global_load_lds(GPTR(gA1 + kk), LPTR(lA1), 16, 0, 0);
        __builtin_amdgcn_global_load_lds(GPTR(gB0 + kk), LPTR(lB0), 16, 0, 0);
        __syncthreads();
        bf16x8 af[4], bfv[2];
#pragma unroll
        for (int mt = 0; mt < 4; ++mt)
            af[mt] = __builtin_bit_cast(bf16x8,
                *reinterpret_cast<const uint4*>(As + (wm * 64 + mt * 16 + lm) * 32 + quad * 8));
#pragma unroll
        for (int nt = 0; nt < 2; ++nt)
            bfv[nt] = __builtin_bit_cast(bf16x8,
                *reinterpret_cast<const uint4*>(Bs + (wn * 32 + nt * 16 + lm) * 32 + quad * 8));
#pragma unroll
        for (int mt = 0; mt < 4; ++mt)
#pragma unroll
            for (int nt = 0; nt < 2; ++nt)
                acc[mt][nt] = __builtin_amdgcn_mfma_f32_16x16x32_bf16(af[mt], bfv[nt], acc[mt][nt], 0, 0, 0);
        __syncthreads();
    }
#pragma unroll
    for (int mt = 0; mt < 4; ++mt)
#pragma unroll
        for (int nt = 0; nt < 2; ++nt)
#pragma unroll
            for (int r = 0; r < 4; ++r) {
                int rg = m0 + wm * 64 + mt * 16 + quad * 4 + r;
                int cg = n0 + wn * 32 + nt * 16 + lm;
                C[(long)rg * Dn + cg] = acc[mt][nt][r];
            }
}

// ---------------- flash attention: uniform paired blocks, 1 frag/wave, registers-only ----------------
// Block = 4 independent waves (no LDS, no barriers). Wave w of block (bx,h,b) owns q-rows
// qb*64 + w*16 .. +15 for qb = 31-bx (pass 0) then bx (pass 1): every block = exactly 33 k-tiles
// -> uniform makespan, 1024 blocks = 4/CU = 16 waves/CU steady residency (fixes r5/r6 tail).
// S^T = K·Q^T (q on lane&15) + permuted-K PV via 16x16x32 (HW-verified r5); K&V ping-pong prefetch.
__global__ __launch_bounds__(256) void attn(
    const unsigned short* __restrict__ Qn, const unsigned short* __restrict__ Kn,
    const unsigned short* __restrict__ Vt, unsigned short* __restrict__ Y) {
    const int bx = blockIdx.x, h = blockIdx.y, b = blockIdx.z;
    const int tid = threadIdx.x, w = tid >> 6, l = tid & 63;
    const int lm = l & 15, quad = l >> 4;
    const long bh = b * NHn + h;
    const unsigned short* Qh = Qn + bh * Tn * 32;
    const unsigned short* Kh = Kn + bh * Tn * 32;
    const unsigned short* Vh = Vt + bh * 32 * Tn;

    for (int pass = 0; pass < 2; ++pass) {
        const int qb = pass ? bx : 31 - bx;  // big tile first
        const int q0 = qb * 64 + w * 16;

        bf16x8 qf = __builtin_bit_cast(bf16x8,
            *reinterpret_cast<const uint4*>(Qh + (q0 + lm) * 32 + quad * 8));
        float ss = 0.f;
#pragma unroll
        for (int j = 0; j < 8; ++j) { float v = (float)qf[j]; ss += v * v; }
        ss += __shfl_xor(ss, 16);
        ss += __shfl_xor(ss, 32);
        const float negM = -__builtin_sqrtf(ss * 32.0f);  // |q_row|*sqrt(32) >= any score (rmsnormed K)
        const int qrow = q0 + lm;  // this lane's q-row in S^T

        float lpart = 0.f;
        f32x4 o0 = {0.f, 0.f, 0.f, 0.f}, o1 = {0.f, 0.f, 0.f, 0.f};

        const int kend = q0 + 15;
        uint4 ka[4], kb[4];
        uint2 va[8], vb[8];

        auto load_t = [&](uint4* kd, uint2* vd, int k0) {
#pragma unroll
            for (int i = 0; i < 4; ++i)
                kd[i] = *reinterpret_cast<const uint4*>(Kh + (k0 + i * 16 + lm) * 32 + quad * 8);
#pragma unroll
            for (int i = 0; i < 4; ++i)
#pragma unroll
                for (int nh_ = 0; nh_ < 2; ++nh_)
                    vd[i * 2 + nh_] = *reinterpret_cast<const uint2*>(
                        Vh + (nh_ * 16 + lm) * Tn + k0 + i * 16 + quad * 4);
        };

        auto compute_t = [&](const uint4* kd, const uint2* vd, int k0) {
            f32x4 s[4];
#pragma unroll
            for (int i = 0; i < 4; ++i) {
                f32x4 zz = {0.f, 0.f, 0.f, 0.f};
                s[i] = __builtin_amdgcn_mfma_f32_16x16x32_bf16(
                    __builtin_bit_cast(bf16x8, kd[i]), qf, zz, 0, 0, 0);
            }
            const bool full = (k0 + 63) <= q0;
            float ls = lpart;
            short8v pk[2];  // pk[kh][(i&1)*4+r] = P at k = k0+kh*32+(i&1)*16+quad*4+r
#pragma unroll
            for (int i = 0; i < 4; ++i)
#pragma unroll
                for (int r = 0; r < 4; ++r) {
                    float p = __builtin_amdgcn_exp2f(s[i][r] + negM);
                    if (!full) {
                        int kc = k0 + i * 16 + quad * 4 + r;
                        p = (kc <= qrow) ? p : 0.0f;
                    }
                    ls += p;
                    pk[i >> 1][(i & 1) * 4 + r] = (short)f2bf_fast(p);
                }
            lpart = ls;
#pragma unroll
            for (int kh = 0; kh < 2; ++kh) {
                bf16x8 pa = __builtin_bit_cast(bf16x8, pk[kh]);
#pragma unroll
                for (int nh_ = 0; nh_ < 2; ++nh_) {
                    uint2 b0 = vd[(2 * kh) * 2 + nh_], b1 = vd[(2 * kh + 1) * 2 + nh_];
                    uint4 bb = {b0.x, b0.y, b1.x, b1.y};
                    f32x4& oo = nh_ ? o1 : o0;
                    oo = __builtin_amdgcn_mfma_f32_16x16x32_bf16(
                        pa, __builtin_bit_cast(bf16x8, bb), oo, 0, 0, 0);
                }
            }
        };

        load_t(ka, va, 0);
        int k0 = 0;
        while (true) {
            int nk = k0 + 64;
            if (nk <= kend) load_t(kb, vb, nk);
            compute_t(ka, va, k0);
            if (nk > kend) break;
            k0 = nk;
            nk = k0 + 64;
            if (nk <= kend) load_t(ka, va, nk);
            compute_t(kb, vb, k0);
            if (nk > kend) break;
            k0 = nk;
        }

        float lsum = lpart;
        lsum += __shfl_xor(lsum, 16);
        lsum += __shfl_xor(lsum, 32);
#pragma unroll
        for (int r = 0; r < 4; ++r) {
            float inv = 1.0f / __shfl(lsum, quad * 4 + r, 16);
            int qr = q0 + quad * 4 + r;
            long base = ((long)(b * Tn + qr) * NHn + h) * 32;
            Y[base + lm] = f2bf(o0[r] * inv);
            Y[base + 16 + lm] = f2bf(o1[r] * inv);
        }
    }
}

extern "C" void kernel_launch(void* const* d_in, const int* in_sizes, int n_in,
                              void* d_out, int out_size, void* d_ws, size_t ws_size,
                              hipStream_t stream) {
    (void)in_sizes; (void)n_in; (void)out_size; (void)ws_size;
    const float* x = (const float*)d_in[0];
    const float* Wq = (const float*)d_in[1];
    const float* Wk = (const float*)d_in[2];
    const float* Wv = (const float*)d_in[3];
    const float* Wp = (const float*)d_in[4];
    const float* gain = (const float*)d_in[5];
    const float* cosp = (const float*)d_in[6];
    const float* sinp = (const float*)d_in[7];

    char* ws = (char*)d_ws;
    const size_t SZ = (size_t)Mn * Dn * 2;  // 8 MB
    unsigned short* xb = (unsigned short*)ws;
    unsigned short* wall = (unsigned short*)(ws + SZ);  // [Wq|Wk|Wv|Wp], 8 MB
    unsigned short* qn = (unsigned short*)(ws + 2 * SZ);
    unsigned short* kn = qn + (size_t)Mn * Dn;
    unsigned short* vt = kn + (size_t)Mn * Dn;
    unsigned short* ybuf = vt + (size_t)Mn * Dn;
    // total ws: 48 MB

    cast_all<<<8192, 256, 0, stream>>>(x, Wq, Wk, Wv, Wp, xb, wall);

    gemm_qkv<<<dim3(Mn / 128, Dn / 128, 3), 256, 0, stream>>>(
        xb, wall, qn, kn, vt, gain, cosp, sinp);

    attn<<<dim3(16, NHn, 2), 256, 0, stream>>>(qn, kn, vt, ybuf);

    gemm_proj<<<dim3(Mn / 128, Dn / 64), 256, 0, stream>>>(
        ybuf, wall + (size_t)3 * Dn * Dn, (float*)d_out);
}

// Round 8
// 271.098 us; speedup vs baseline: 1.0752x; 1.0622x over previous
//
#include <hip/hip_runtime.h>

#define DEV __device__ __forceinline__

typedef __bf16 bf16x8 __attribute__((ext_vector_type(8)));
typedef float f32x4 __attribute__((ext_vector_type(4)));

static constexpr int Tn = 2048;
static constexpr int Dn = 1024;
static constexpr int NHn = 32;
static constexpr int Mn = 2 * Tn;  // B*T = 4096
static constexpr float QSCALE = 0.17677669529663687f * 1.4426950408889634f;  // 1/sqrt(32)*log2e

DEV unsigned short f2bf(float f) {  // RNE
    unsigned int u = __builtin_bit_cast(unsigned int, f);
    u = u + 0x7FFFu + ((u >> 16) & 1u);
    return (unsigned short)(u >> 16);
}
DEV unsigned short f2bf_fast(float f) {  // round-half-up: 2 ops, fine for P in [0,1]
    unsigned int u = __builtin_bit_cast(unsigned int, f);
    return (unsigned short)((u + 0x8000u) >> 16);
}

#define GPTR(p) ((const __attribute__((address_space(1))) void*)(p))
#define LPTR(p) ((__attribute__((address_space(3))) void*)(p))

// ---------------- single fused cast: x (1M float4) + 4 weights (1M float4) ----------------
__global__ __launch_bounds__(256) void cast_all(
    const float* __restrict__ x, const float* __restrict__ Wq, const float* __restrict__ Wk,
    const float* __restrict__ Wv, const float* __restrict__ Wp,
    unsigned short* __restrict__ xb, unsigned short* __restrict__ wall) {
    int i = blockIdx.x * 256 + threadIdx.x;  // [0, 2M)
    const float* src;
    ushort4* dst;
    if (i < (1 << 20)) {
        src = x + (size_t)i * 4;
        dst = reinterpret_cast<ushort4*>(xb) + i;
    } else {
        int j = i - (1 << 20);
        int sel = j >> 18, off = j & ((1 << 18) - 1);
        const float* w = (sel == 0) ? Wq : (sel == 1) ? Wk : (sel == 2) ? Wv : Wp;
        src = w + (size_t)off * 4;
        dst = reinterpret_cast<ushort4*>(wall) + ((size_t)sel << 18) + off;
    }
    float4 v = *reinterpret_cast<const float4*>(src);
    ushort4 o;
    o.x = f2bf(v.x); o.y = f2bf(v.y); o.z = f2bf(v.z); o.w = f2bf(v.w);
    *dst = o;
}

// ---------------- fused QKV GEMM (m97 pattern) + RMSNorm/RoPE/relayout epilogue ----------------
__global__ __launch_bounds__(256, 3) void gemm_qkv(
    const unsigned short* __restrict__ A, const unsigned short* __restrict__ Wall,
    unsigned short* __restrict__ Qn, unsigned short* __restrict__ Kn, unsigned short* __restrict__ Vt,
    const float* __restrict__ gain, const float* __restrict__ cosp, const float* __restrict__ sinp) {
    const int z = blockIdx.z;
    const unsigned short* Bm = Wall + (size_t)z * (Dn * Dn);
    const int m0 = blockIdx.x * 128, n0 = blockIdx.y * 128;
    const int tid = threadIdx.x, w = tid >> 6, l = tid & 63;
    const int wm = w & 1, wn = w >> 1, lm = l & 15, quad = l >> 4;

    __shared__ __align__(16) unsigned short As[128 * 32];  // lane-linear, no padding (global_load_lds)
    __shared__ __align__(16) unsigned short Bs[128 * 32];

    f32x4 acc[4][4] = {};

    const int r0 = (w * 2 + 0) * 16 + (l >> 2);
    const int r1 = (w * 2 + 1) * 16 + (l >> 2);
    const int c0 = (l & 3) * 8;
    const unsigned short* gA0 = A + (long)(m0 + r0) * Dn + c0;
    const unsigned short* gA1 = A + (long)(m0 + r1) * Dn + c0;
    const unsigned short* gB0 = Bm + (long)(n0 + r0) * Dn + c0;
    const unsigned short* gB1 = Bm + (long)(n0 + r1) * Dn + c0;
    unsigned short* lA0 = As + (w * 2 + 0) * 16 * 32;
    unsigned short* lA1 = As + (w * 2 + 1) * 16 * 32;
    unsigned short* lB0 = Bs + (w * 2 + 0) * 16 * 32;
    unsigned short* lB1 = Bs + (w * 2 + 1) * 16 * 32;

    for (int kk = 0; kk < Dn; kk += 32) {
        __builtin_amdgcn_global_load_lds(GPTR(gA0 + kk), LPTR(lA0), 16, 0, 0);
        __builtin_amdgcn_global_load_lds(GPTR(gA1 + kk), LPTR(lA1), 16, 0, 0);
        __builtin_amdgcn_global_load_lds(GPTR(gB0 + kk), LPTR(lB0), 16, 0, 0);
        __builtin_amdgcn_global_load_lds(GPTR(gB1 + kk), LPTR(lB1), 16, 0, 0);
        __syncthreads();
        bf16x8 af[4], bfv[4];
#pragma unroll
        for (int mt = 0; mt < 4; ++mt)
            af[mt] = __builtin_bit_cast(bf16x8,
                *reinterpret_cast<const uint4*>(As + (wm * 64 + mt * 16 + lm) * 32 + quad * 8));
#pragma unroll
        for (int nt = 0; nt < 4; ++nt)
            bfv[nt] = __builtin_bit_cast(bf16x8,
                *reinterpret_cast<const uint4*>(Bs + (wn * 64 + nt * 16 + lm) * 32 + quad * 8));
#pragma unroll
        for (int mt = 0; mt < 4; ++mt)
#pragma unroll
            for (int nt = 0; nt < 4; ++nt)
                acc[mt][nt] = __builtin_amdgcn_mfma_f32_16x16x32_bf16(af[mt], bfv[nt], acc[mt][nt], 0, 0, 0);
        __syncthreads();
    }

    if (z == 2) {
#pragma unroll
        for (int mt = 0; mt < 4; ++mt) {
            int row0 = m0 + wm * 64 + mt * 16 + quad * 4;
            int b_ = row0 >> 11, t_ = row0 & (Tn - 1);
#pragma unroll
            for (int nt = 0; nt < 4; ++nt) {
                int col = n0 + wn * 64 + nt * 16 + lm;
                int hh = col >> 5, dd = col & 31;
                ushort4 o4;
                o4.x = f2bf(acc[mt][nt][0]); o4.y = f2bf(acc[mt][nt][1]);
                o4.z = f2bf(acc[mt][nt][2]); o4.w = f2bf(acc[mt][nt][3]);
                *reinterpret_cast<ushort4*>(&Vt[((long)(b_ * NHn + hh) * 32 + dd) * Tn + t_]) = o4;
            }
        }
    } else {
        unsigned short* dst = z ? Kn : Qn;
#pragma unroll
        for (int mt = 0; mt < 4; ++mt)
#pragma unroll
            for (int r = 0; r < 4; ++r) {
                int row = m0 + wm * 64 + mt * 16 + quad * 4 + r;
                int b_ = row >> 11, t_ = row & (Tn - 1);
                float c = cosp[t_ * 16 + lm], s = sinp[t_ * 16 + lm];
#pragma unroll
                for (int g = 0; g < 2; ++g) {
                    float x1 = acc[mt][2 * g][r], x2 = acc[mt][2 * g + 1][r];
                    float ssv = x1 * x1 + x2 * x2;
#pragma unroll
                    for (int off = 8; off >= 1; off >>= 1) ssv += __shfl_xor(ssv, off, 16);
                    float rinv = rsqrtf(ssv * (1.0f / 32.0f) + 1e-6f);
                    x1 *= rinv; x2 *= rinv;
                    float o1 = x1 * c - x2 * s;
                    float o2 = x2 * c + x1 * s;
                    int hh = (n0 + wn * 64 + g * 32) >> 5;
                    if (z == 0) { float gs = gain[hh] * QSCALE; o1 *= gs; o2 *= gs; }
                    long base = ((long)(b_ * NHn + hh) * Tn + t_) * 32;
                    dst[base + lm] = f2bf(o1);
                    dst[base + 16 + lm] = f2bf(o2);
                }
            }
    }
}

// ---------------- proj GEMM: 128x64 tile (512 blocks -> 2 blocks/CU), fp32 out ----------------
__global__ __launch_bounds__(256, 3) void gemm_proj(
    const unsigned short* __restrict__ A, const unsigned short* __restrict__ Bm,
    float* __restrict__ C) {
    const int m0 = blockIdx.x * 128, n0 = blockIdx.y * 64;
    const int tid = threadIdx.x, w = tid >> 6, l = tid & 63;
    const int wm = w & 1, wn = w >> 1, lm = l & 15, quad = l >> 4;

    __shared__ __align__(16) unsigned short As[128 * 32];
    __shared__ __align__(16) unsigned short Bs[64 * 32];

    f32x4 acc[4][2] = {};

    const int r0 = (w * 2 + 0) * 16 + (l >> 2);
    const int r1 = (w * 2 + 1) * 16 + (l >> 2);
    const int rb = w * 16 + (l >> 2);
    const int c0 = (l & 3) * 8;
    const unsigned short* gA0 = A + (long)(m0 + r0) * Dn + c0;
    const unsigned short* gA1 = A + (long)(m0 + r1) * Dn + c0;
    const unsigned short* gB0 = Bm + (long)(n0 + rb) * Dn + c0;
    unsigned short* lA0 = As + (w * 2 + 0) * 16 * 32;
    unsigned short* lA1 = As + (w * 2 + 1) * 16 * 32;
    unsigned short* lB0 = Bs + w * 16 * 32;

    for (int kk = 0; kk < Dn; kk += 32) {
        __builtin_amdgcn_global_load_lds(GPTR(gA0 + kk), LPTR(lA0), 16, 0, 0);
        __builtin_amdgcn_global_load_lds(GPTR(gA1 + kk), LPTR(lA1), 16, 0, 0);
        __builtin_amdgcn_global_load_lds(GPTR(gB0 + kk), LPTR(lB0), 16, 0, 0);
        __syncthreads();
        bf16x8 af[4], bfv[2];
#pragma unroll
        for (int mt = 0; mt < 4; ++mt)
            af[mt] = __builtin_bit_cast(bf16x8,
                *reinterpret_cast<const uint4*>(As + (wm * 64 + mt * 16 + lm) * 32 + quad * 8));
#pragma unroll
        for (int nt = 0; nt < 2; ++nt)
            bfv[nt] = __builtin_bit_cast(bf16x8,
                *reinterpret_cast<const uint4*>(Bs + (wn * 32 + nt * 16 + lm) * 32 + quad * 8));
#pragma unroll
        for (int mt = 0; mt < 4; ++mt)
#pragma unroll
            for (int nt = 0; nt < 2; ++nt)
                acc[mt][nt] = __builtin_amdgcn_mfma_f32_16x16x32_bf16(af[mt], bfv[nt], acc[mt][nt], 0, 0, 0);
        __syncthreads();
    }
#pragma unroll
    for (int mt = 0; mt < 4; ++mt)
#pragma unroll
        for (int nt = 0; nt < 2; ++nt)
#pragma unroll
            for (int r = 0; r < 4; ++r) {
                int rg = m0 + wm * 64 + mt * 16 + quad * 4 + r;
                int cg = n0 + wn * 32 + nt * 16 + lm;
                C[(long)rg * Dn + cg] = acc[mt][nt][r];
            }
}

// ---------------- flash attention: R3 wave structure + k-split for 2x wave parallelism ----------------
// Block = 4 waves = 2 row-groups (rg) x 2 k-splits (sp). Wave (rg,sp) processes 32 q-rows
// (2x16-row frags, R3's proven shared-K/V structure w/ LDS P round-trip + ping-pong prefetch)
// over k-tiles j = sp, sp+2, ... (even/odd split). Partial (o, l) merged via LDS (same negM on
// both splits -> exp-domain add is exact). Passes (31-bx, bx) -> 1024 uniform blocks, ALL
// 4096 waves resident = 16 waves/CU (2x R3's depth; the exp2-heavy inner loop needs the waves).
__global__ __launch_bounds__(256, 4) void attn(
    const unsigned short* __restrict__ Qn, const unsigned short* __restrict__ Kn,
    const unsigned short* __restrict__ Vt, unsigned short* __restrict__ Y) {
    const int bx = blockIdx.x, h = blockIdx.y, b = blockIdx.z;
    const int tid = threadIdx.x, w = tid >> 6, l = tid & 63;
    const int rg = w & 1, sp = w >> 1;
    const int lm = l & 15, quad = l >> 4;
    const long bh = b * NHn + h;
    const unsigned short* Qh = Qn + bh * Tn * 32;
    const unsigned short* Kh = Kn + bh * Tn * 32;
    const unsigned short* Vh = Vt + bh * 32 * Tn;
    __shared__ __align__(16) unsigned short Pl[4][16][76];  // per-wave P tile
    __shared__ float cbuf[2][64][24];                       // split-combine buffer per row-group
    unsigned short* Pw = &Pl[w][0][0];

    for (int pass = 0; pass < 2; ++pass) {
        const int qb = pass ? bx : 31 - bx;  // uniform pair: qb + (31-qb) + 2 = 33 tiles/block-slot
        const int q0 = qb * 64 + rg * 32;

        bf16x8 qf[2];
        float negM[2][4];
        float lpart[2][4] = {};
        f32x4 o[2][2] = {{{0.f, 0.f, 0.f, 0.f}, {0.f, 0.f, 0.f, 0.f}},
                         {{0.f, 0.f, 0.f, 0.f}, {0.f, 0.f, 0.f, 0.f}}};
#pragma unroll
        for (int t = 0; t < 2; ++t) {
            qf[t] = __builtin_bit_cast(bf16x8,
                *reinterpret_cast<const uint4*>(Qh + (q0 + t * 16 + lm) * 32 + quad * 8));
            float ss = 0.f;
#pragma unroll
            for (int j = 0; j < 8; ++j) { float v = (float)qf[t][j]; ss += v * v; }
            ss += __shfl_xor(ss, 16);
            ss += __shfl_xor(ss, 32);
            float Mv = __builtin_sqrtf(ss * 32.0f);  // |q_row|*sqrt(32) bounds all scores (rms K)
#pragma unroll
            for (int r = 0; r < 4; ++r) negM[t][r] = -__shfl(Mv, quad * 4 + r, 16);
        }

        uint4 ka[4], kb[4], va[4], vb[4];

        auto load_t = [&](uint4* kd, uint4* vd, int k0) {
#pragma unroll
            for (int i = 0; i < 4; ++i)
                kd[i] = *reinterpret_cast<const uint4*>(Kh + (k0 + i * 16 + lm) * 32 + quad * 8);
#pragma unroll
            for (int kf2 = 0; kf2 < 2; ++kf2)
#pragma unroll
                for (int nh_ = 0; nh_ < 2; ++nh_)
                    vd[kf2 * 2 + nh_] = *reinterpret_cast<const uint4*>(
                        Vh + (nh_ * 16 + lm) * Tn + k0 + kf2 * 32 + quad * 8);
        };

        auto compute_t = [&](const uint4* kd, const uint4* vd, int k0) {
#pragma unroll
            for (int t = 0; t < 2; ++t) {
                if (k0 > q0 + t * 16 + 15) continue;
                f32x4 s[4];
#pragma unroll
                for (int i = 0; i < 4; ++i) {
                    f32x4 zz = {0.f, 0.f, 0.f, 0.f};
                    s[i] = __builtin_amdgcn_mfma_f32_16x16x32_bf16(
                        qf[t], __builtin_bit_cast(bf16x8, kd[i]), zz, 0, 0, 0);
                }
                if ((k0 + 63) <= (q0 + t * 16)) {  // full tile: no masking (94% of tiles)
#pragma unroll
                    for (int i = 0; i < 4; ++i)
#pragma unroll
                        for (int r = 0; r < 4; ++r) {
                            float p = __builtin_amdgcn_exp2f(s[i][r] + negM[t][r]);
                            lpart[t][r] += p;
                            Pw[(quad * 4 + r) * 76 + i * 16 + lm] = f2bf_fast(p);
                        }
                } else {  // diagonal tile: causal mask
#pragma unroll
                    for (int i = 0; i < 4; ++i)
#pragma unroll
                        for (int r = 0; r < 4; ++r) {
                            int qrow = q0 + t * 16 + quad * 4 + r;
                            int kc = k0 + i * 16 + lm;
                            float p = __builtin_amdgcn_exp2f(s[i][r] + negM[t][r]);
                            p = (kc <= qrow) ? p : 0.0f;
                            lpart[t][r] += p;
                            Pw[(quad * 4 + r) * 76 + i * 16 + lm] = f2bf_fast(p);
                        }
                }
#pragma unroll
                for (int kf2 = 0; kf2 < 2; ++kf2) {
                    bf16x8 pf = __builtin_bit_cast(bf16x8,
                        *reinterpret_cast<const uint4*>(Pw + lm * 76 + kf2 * 32 + quad * 8));
#pragma unroll
                    for (int nh_ = 0; nh_ < 2; ++nh_)
                        o[t][nh_] = __builtin_amdgcn_mfma_f32_16x16x32_bf16(
                            pf, __builtin_bit_cast(bf16x8, vd[kf2 * 2 + nh_]), o[t][nh_], 0, 0, 0);
                }
            }
        };

        // k-split ping-pong: this wave handles tiles j = sp, sp+2, ...
        int j = sp;
        if (j <= qb) {
            load_t(ka, va, j * 64);
            while (true) {
                int jn = j + 2;
                if (jn <= qb) load_t(kb, vb, jn * 64);
                compute_t(ka, va, j * 64);
                if (jn > qb) break;
                j = jn;
                jn = j + 2;
                if (jn <= qb) load_t(ka, va, jn * 64);
                compute_t(kb, vb, j * 64);
                if (jn > qb) break;
                j = jn;
            }
        }

        // merge the two k-splits of this row-group via LDS
        if (sp == 1) {
            float* cb = &cbuf[rg][l][0];
#pragma unroll
            for (int t = 0; t < 2; ++t)
#pragma unroll
                for (int nh_ = 0; nh_ < 2; ++nh_)
#pragma unroll
                    for (int r = 0; r < 4; ++r) cb[t * 8 + nh_ * 4 + r] = o[t][nh_][r];
#pragma unroll
            for (int t = 0; t < 2; ++t)
#pragma unroll
                for (int r = 0; r < 4; ++r) cb[16 + t * 4 + r] = lpart[t][r];
        }
        __syncthreads();
        if (sp == 0) {
            const float* cb = &cbuf[rg][l][0];
#pragma unroll
            for (int t = 0; t < 2; ++t) {
#pragma unroll
                for (int nh_ = 0; nh_ < 2; ++nh_)
#pragma unroll
                    for (int r = 0; r < 4; ++r) o[t][nh_][r] += cb[t * 8 + nh_ * 4 + r];
#pragma unroll
                for (int r = 0; r < 4; ++r) {
                    float ls = lpart[t][r] + cb[16 + t * 4 + r];
#pragma unroll
                    for (int off = 8; off >= 1; off >>= 1) ls += __shfl_xor(ls, off, 16);
                    float inv = 1.0f / ls;
                    int qr = q0 + t * 16 + quad * 4 + r;
                    long base = ((long)(b * Tn + qr) * NHn + h) * 32;
                    Y[base + lm] = f2bf(o[t][0][r] * inv);
                    Y[base + 16 + lm] = f2bf(o[t][1][r] * inv);
                }
            }
        }
        __syncthreads();  // cbuf reused next pass
    }
}

extern "C" void kernel_launch(void* const* d_in, const int* in_sizes, int n_in,
                              void* d_out, int out_size, void* d_ws, size_t ws_size,
                              hipStream_t stream) {
    (void)in_sizes; (void)n_in; (void)out_size; (void)ws_size;
    const float* x = (const float*)d_in[0];
    const float* Wq = (const float*)d_in[1];
    const float* Wk = (const float*)d_in[2];
    const float* Wv = (const float*)d_in[3];
    const float* Wp = (const float*)d_in[4];
    const float* gain = (const float*)d_in[5];
    const float* cosp = (const float*)d_in[6];
    const float* sinp = (const float*)d_in[7];

    char* ws = (char*)d_ws;
    const size_t SZ = (size_t)Mn * Dn * 2;  // 8 MB
    unsigned short* xb = (unsigned short*)ws;
    unsigned short* wall = (unsigned short*)(ws + SZ);  // [Wq|Wk|Wv|Wp], 8 MB
    unsigned short* qn = (unsigned short*)(ws + 2 * SZ);
    unsigned short* kn = qn + (size_t)Mn * Dn;
    unsigned short* vt = kn + (size_t)Mn * Dn;
    unsigned short* ybuf = vt + (size_t)Mn * Dn;
    // total ws: 48 MB

    cast_all<<<8192, 256, 0, stream>>>(x, Wq, Wk, Wv, Wp, xb, wall);

    gemm_qkv<<<dim3(Mn / 128, Dn / 128, 3), 256, 0, stream>>>(
        xb, wall, qn, kn, vt, gain, cosp, sinp);

    attn<<<dim3(16, NHn, 2), 256, 0, stream>>>(qn, kn, vt, ybuf);

    gemm_proj<<<dim3(Mn / 128, Dn / 64), 256, 0, stream>>>(
        ybuf, wall + (size_t)3 * Dn * Dn, (float*)d_out);
}